// Round 1
// baseline (950.492 us; speedup 1.0000x reference)
//
#include <hip/hip_runtime.h>
#include <math.h>

#define Bz 8
#define Cc 512
#define C8c 64
#define Hh 64
#define Ww 64
#define HW 4096

// ---------------------------------------------------------------------------
// Projection: outT[b][p][o] = bias[o] + sum_c W[o][c] * in[b][c][p]
// One thread per pixel p, OT outputs per thread; weights via scalar loads.
// ---------------------------------------------------------------------------
template<int COUT, int OT>
__global__ __launch_bounds__(256) void proj_kernel(
    const float* __restrict__ in, const float* __restrict__ Wm,
    const float* __restrict__ bias, float* __restrict__ outT)
{
    const int p  = blockIdx.x * 256 + threadIdx.x;
    const int o0 = blockIdx.y * OT;
    const int b  = blockIdx.z;
    const float* __restrict__ inb = in + (size_t)b * Cc * HW + p;
    const float* __restrict__ wr  = Wm + (size_t)o0 * Cc;
    float acc[OT];
#pragma unroll
    for (int j = 0; j < OT; ++j) acc[j] = bias[o0 + j];
#pragma unroll 4
    for (int c = 0; c < Cc; ++c) {
        float x = inb[(size_t)c * HW];
#pragma unroll
        for (int j = 0; j < OT; ++j)
            acc[j] = fmaf(wr[(size_t)j * Cc + c], x, acc[j]);
    }
    float* op = outT + ((size_t)b * HW + p) * COUT + o0;
#pragma unroll
    for (int j = 0; j < OT; ++j) op[j] = acc[j];
}

// ---------------------------------------------------------------------------
// Scores. mode0 (blockIdx.z==0): block=(b,w): eH[h][k]=dot_c(pq[:,h,w],pk[:,k,w])
//         mode1: block=(b,h): eW[w][k]=dot_c(pq[:,h,w],pk[:,h,k])
// S layout: [b][h][w][128], first 64 = eH, next 64 = eW. Mask applied in softmax.
// ---------------------------------------------------------------------------
__global__ __launch_bounds__(256) void scores_kernel(
    const float* __restrict__ pqT, const float* __restrict__ pkT,
    float* __restrict__ S)
{
    const int x    = blockIdx.x;   // w (mode0) or h (mode1)
    const int b    = blockIdx.y;
    const int mode = blockIdx.z;
    __shared__ float Q[64][65];
    __shared__ float K[64][65];
    for (int idx = threadIdx.x; idx < 4096; idx += 256) {
        int r = idx >> 6, c = idx & 63;
        int p = mode ? (x * Ww + r) : (r * Ww + x);
        size_t g = ((size_t)b * HW + p) * 64 + c;
        Q[r][c] = pqT[g];
        K[r][c] = pkT[g];
    }
    __syncthreads();
    const int qr = threadIdx.x >> 2;        // query row: h (mode0) / w (mode1)
    const int k0 = (threadIdx.x & 3) * 16;  // key range
    float acc[16];
#pragma unroll
    for (int j = 0; j < 16; ++j) acc[j] = 0.f;
#pragma unroll 4
    for (int c = 0; c < 64; ++c) {
        float qv = Q[qr][c];
#pragma unroll
        for (int j = 0; j < 16; ++j)
            acc[j] = fmaf(qv, K[k0 + j][c], acc[j]);
    }
    size_t o = mode ? (((size_t)(b * Hh + x) * Ww + qr) * 128 + 64 + k0)
                    : (((size_t)(b * Hh + qr) * Ww + x) * 128 + k0);
#pragma unroll
    for (int j = 0; j < 16; ++j) S[o + j] = acc[j];
}

// ---------------------------------------------------------------------------
// Softmax over 128 entries per (b,h,w); diag mask (eH[k==h] = -inf) applied here.
// One 64-lane wave per row, 2 entries per lane, shuffle reductions.
// ---------------------------------------------------------------------------
__global__ __launch_bounds__(256) void softmax_kernel(float* __restrict__ S)
{
    const int wave = threadIdx.x >> 6;
    const int lane = threadIdx.x & 63;
    const size_t row = (size_t)blockIdx.x * 4 + wave;   // (b*H + h)*W + w
    const int h = (int)((row / Ww) % Hh);
    float* p = S + row * 128;
    float s0 = p[lane], s1 = p[lane + 64];
    if (lane == h) s0 = -INFINITY;
    float m = fmaxf(s0, s1);
#pragma unroll
    for (int off = 32; off > 0; off >>= 1) m = fmaxf(m, __shfl_xor(m, off));
    float e0 = __expf(s0 - m), e1 = __expf(s1 - m);
    float s = e0 + e1;
#pragma unroll
    for (int off = 32; off > 0; off >>= 1) s += __shfl_xor(s, off);
    float inv = 1.0f / s;
    p[lane]      = e0 * inv;
    p[lane + 64] = e1 * inv;
}

// ---------------------------------------------------------------------------
// outH: block=(b,w): TH[b][h][w][c] = sum_k pvT[b][k*W+w][c] * aH[h][k]
// 4x4 register tile per thread (4 c x 4 h), 8 c-tiles of 64.
// ---------------------------------------------------------------------------
__global__ __launch_bounds__(256) void outH_kernel(
    const float* __restrict__ S, const float* __restrict__ pvT,
    float* __restrict__ TH)
{
    const int w = blockIdx.x;
    const int b = blockIdx.y;
    __shared__ float A[64][65];   // [h][k]
    __shared__ float P[64][68];   // [k][c']
    for (int idx = threadIdx.x; idx < 4096; idx += 256) {
        int h = idx >> 6, k = idx & 63;
        A[h][k] = S[(((size_t)(b * Hh + h) * Ww) + w) * 128 + k];
    }
    const int cg = (threadIdx.x & 15) * 4;   // c' base (coalesced writes over c)
    const int hg = (threadIdx.x >> 4) * 4;   // h base
    for (int ct = 0; ct < 8; ++ct) {
        __syncthreads();
        for (int idx = threadIdx.x; idx < 1024; idx += 256) {
            int k = idx >> 4, c4 = idx & 15;
            *(float4*)(&P[k][c4 * 4]) =
                *(const float4*)(pvT + ((size_t)b * HW + k * Ww + w) * 512 + ct * 64 + c4 * 4);
        }
        __syncthreads();
        float acc[4][4];
#pragma unroll
        for (int i = 0; i < 4; ++i)
#pragma unroll
            for (int j = 0; j < 4; ++j) acc[i][j] = 0.f;
        for (int k = 0; k < 64; ++k) {
            float4 p4 = *(const float4*)(&P[k][cg]);
            float pvv[4] = {p4.x, p4.y, p4.z, p4.w};
            float av[4];
#pragma unroll
            for (int j = 0; j < 4; ++j) av[j] = A[hg + j][k];
#pragma unroll
            for (int i = 0; i < 4; ++i)
#pragma unroll
                for (int j = 0; j < 4; ++j)
                    acc[i][j] = fmaf(pvv[i], av[j], acc[i][j]);
        }
#pragma unroll
        for (int j = 0; j < 4; ++j) {
            float4 o4 = make_float4(acc[0][j], acc[1][j], acc[2][j], acc[3][j]);
            *(float4*)(TH + (((size_t)(b * Hh + hg + j) * Ww) + w) * 512 + ct * 64 + cg) = o4;
        }
    }
}

// ---------------------------------------------------------------------------
// outW + finalize: block=(b,h):
// out[b][c][h][w] = gamma*(TH[b][h][w][c] + sum_k pvT[b][h*W+k][c]*aW[w][k]) + v
// ---------------------------------------------------------------------------
__global__ __launch_bounds__(256) void outW_final_kernel(
    const float* __restrict__ S, const float* __restrict__ pvT,
    const float* __restrict__ TH, const float* __restrict__ vin,
    const float* __restrict__ gamma_p, float* __restrict__ out)
{
    const int h = blockIdx.x;
    const int b = blockIdx.y;
    const float gamma = gamma_p[0];
    __shared__ float A[64][65];    // [w][k]
    __shared__ float P[64][68];    // [k][c']
    __shared__ float T2[64][68];   // [w][c']
    for (int idx = threadIdx.x; idx < 4096; idx += 256) {
        int w_ = idx >> 6, k = idx & 63;
        A[w_][k] = S[(((size_t)(b * Hh + h) * Ww) + w_) * 128 + 64 + k];
    }
    const int cg = (threadIdx.x >> 4) * 4;   // c' base
    const int wg = (threadIdx.x & 15) * 4;   // w base (coalesced writes over w)
    for (int ct = 0; ct < 8; ++ct) {
        __syncthreads();
        for (int idx = threadIdx.x; idx < 1024; idx += 256) {
            int r = idx >> 4, c4 = idx & 15;
            *(float4*)(&P[r][c4 * 4]) =
                *(const float4*)(pvT + ((size_t)b * HW + h * Ww + r) * 512 + ct * 64 + c4 * 4);
            *(float4*)(&T2[r][c4 * 4]) =
                *(const float4*)(TH + (((size_t)(b * Hh + h) * Ww) + r) * 512 + ct * 64 + c4 * 4);
        }
        __syncthreads();
        float acc[4][4];
#pragma unroll
        for (int i = 0; i < 4; ++i)
#pragma unroll
            for (int j = 0; j < 4; ++j) acc[i][j] = 0.f;
        for (int k = 0; k < 64; ++k) {
            float4 p4 = *(const float4*)(&P[k][cg]);
            float pvv[4] = {p4.x, p4.y, p4.z, p4.w};
            float av[4];
#pragma unroll
            for (int j = 0; j < 4; ++j) av[j] = A[wg + j][k];
#pragma unroll
            for (int i = 0; i < 4; ++i)
#pragma unroll
                for (int j = 0; j < 4; ++j)
                    acc[i][j] = fmaf(pvv[i], av[j], acc[i][j]);
        }
#pragma unroll
        for (int i = 0; i < 4; ++i) {
            int c = ct * 64 + cg + i;
            size_t obase = ((size_t)(b * Cc + c) * HW) + (size_t)h * Ww + wg;
            float4 vv = *(const float4*)(vin + obase);
            float4 o4;
            o4.x = gamma * (acc[i][0] + T2[wg + 0][cg + i]) + vv.x;
            o4.y = gamma * (acc[i][1] + T2[wg + 1][cg + i]) + vv.y;
            o4.z = gamma * (acc[i][2] + T2[wg + 2][cg + i]) + vv.z;
            o4.w = gamma * (acc[i][3] + T2[wg + 3][cg + i]) + vv.w;
            *(float4*)(out + obase) = o4;
        }
    }
}

// ---------------------------------------------------------------------------
extern "C" void kernel_launch(void* const* d_in, const int* in_sizes, int n_in,
                              void* d_out, int out_size, void* d_ws, size_t ws_size,
                              hipStream_t stream)
{
    const float* q   = (const float*)d_in[0];
    const float* k   = (const float*)d_in[1];
    const float* v   = (const float*)d_in[2];
    const float* Wq  = (const float*)d_in[3];
    const float* bq  = (const float*)d_in[4];
    const float* Wk  = (const float*)d_in[5];
    const float* bk  = (const float*)d_in[6];
    const float* Wv  = (const float*)d_in[7];
    const float* bv  = (const float*)d_in[8];
    const float* gam = (const float*)d_in[9];
    float* out = (float*)d_out;
    float* ws  = (float*)d_ws;

    // ws layout (floats): pqT[8][4096][64], pkT same, pvT[8][4096][512],
    // S[8][64][64][128], TH[8][64][64][512]  -> 160 MiB total
    float* pqT = ws;
    float* pkT = ws + 2097152;
    float* pvT = ws + 4194304;
    float* S   = ws + 20971520;
    float* TH  = ws + 25165824;

    proj_kernel<64, 16><<<dim3(16, 4, 8),  256, 0, stream>>>(q, Wq, bq, pqT);
    proj_kernel<64, 16><<<dim3(16, 4, 8),  256, 0, stream>>>(k, Wk, bk, pkT);
    proj_kernel<512,32><<<dim3(16, 16, 8), 256, 0, stream>>>(v, Wv, bv, pvT);
    scores_kernel<<<dim3(64, 8, 2), 256, 0, stream>>>(pqT, pkT, S);
    softmax_kernel<<<8192, 256, 0, stream>>>(S);
    outH_kernel<<<dim3(64, 8), 256, 0, stream>>>(S, pvT, TH);
    outW_final_kernel<<<dim3(64, 8), 256, 0, stream>>>(S, pvT, TH, v, gam, out);
}

// Round 2
// 441.203 us; speedup vs baseline: 2.1543x; 2.1543x over previous
//
#include <hip/hip_runtime.h>
#include <math.h>

#define Bz 8
#define Cc 512
#define Hh 64
#define Ww 64
#define HW 4096
#define BK 64
#define AS (BK + 4)   // LDS row stride in shorts: 136 B rows, 8B-aligned, bank step 2 (uniform)

typedef __attribute__((ext_vector_type(8))) short short8;
typedef __attribute__((ext_vector_type(4))) short short4v;
typedef __attribute__((ext_vector_type(4))) float floatx4;

__device__ inline unsigned short f2bf(float x) {
    unsigned u = __float_as_uint(x);
    return (unsigned short)((u + 0x7FFFu + ((u >> 16) & 1u)) >> 16);   // RNE
}
__device__ inline float b2f(unsigned short h) {
    return __uint_as_float(((unsigned)h) << 16);
}
__device__ inline short8 ld8(const unsigned short* p) {   // 2x ds_read_b64
    short4v a = *(const short4v*)p;
    short4v b = *(const short4v*)(p + 4);
    short8 r;
    r[0]=a[0]; r[1]=a[1]; r[2]=a[2]; r[3]=a[3];
    r[4]=b[0]; r[5]=b[1]; r[6]=b[2]; r[7]=b[3];
    return r;
}

// ---------------------------------------------------------------------------
// Weight pre-convert: Wq,Wk -> bf16 hi+lo (split precision), Wv -> bf16 hi.
// Outputs packed into wsc (aliased with S region; only used before scores).
// layout (shorts): Wqh[32768] Wql[32768] Wkh[32768] Wkl[32768] Wvh[262144]
// ---------------------------------------------------------------------------
__global__ __launch_bounds__(256) void wconv_kernel(
    const float* __restrict__ Wq, const float* __restrict__ Wk,
    const float* __restrict__ Wv, unsigned short* __restrict__ wsc)
{
    const int i = blockIdx.x * 256 + threadIdx.x;
    if (i < 32768) {
        float x = Wq[i];
        unsigned short h = f2bf(x);
        wsc[i] = h;
        wsc[32768 + i] = f2bf(x - b2f(h));
    } else if (i < 65536) {
        int j = i - 32768;
        float x = Wk[j];
        unsigned short h = f2bf(x);
        wsc[65536 + j] = h;
        wsc[98304 + j] = f2bf(x - b2f(h));
    } else {
        int j = i - 65536;
        wsc[131072 + j] = f2bf(Wv[j]);
    }
}

// ---------------------------------------------------------------------------
// MFMA projection GEMM: outT[b][p][o] = bias[o] + sum_c W[o][c]*in[b][c][p]
// Block tile: 128 (p) x BN (o), BK=64 K-steps, 4 waves of 64 x BN/2.
// A (activations): fp32 global -> bf16 (hi[, lo]) transposed into LDS.
// B (weights): pre-converted bf16, staged [o][c] (no transpose).
// SPLIT: 3-pass (Ahi*Bhi + Alo*Bhi + Ahi*Blo) for fp32-grade pq/pk.
// ---------------------------------------------------------------------------
template<int BN, bool SPLIT>
__global__ __launch_bounds__(256) void proj_mfma_kernel(
    const float* __restrict__ in, const unsigned short* __restrict__ Wh,
    const unsigned short* __restrict__ Wl, const float* __restrict__ bias,
    int COUT, float* __restrict__ outT)
{
    constexpr int NS = SPLIT ? 2 : 1;
    constexpr int NT = BN / 32;
    __shared__ unsigned short Ah[NS][128][AS];
    __shared__ unsigned short Bh[NS][BN][AS];
    const int t = threadIdx.x, lane = t & 63, wv = t >> 6;
    const int p0 = blockIdx.x * 128, o0 = blockIdx.y * BN, b = blockIdx.z;
    const float* __restrict__ inb = in + (size_t)b * Cc * HW + p0;

    const int wm = (wv & 1) * 64;
    const int wn = (wv >> 1) * (BN / 2);

    floatx4 acc[4][NT];
#pragma unroll
    for (int i = 0; i < 4; ++i)
#pragma unroll
        for (int j = 0; j < NT; ++j) acc[i][j] = (floatx4)0.f;

    const int ap = t & 127;        // A row (p) this thread stages (lane-consecutive)
    const int aoct0 = t >> 7;      // base c-octet

    for (int kt = 0; kt < Cc / BK; ++kt) {
        const int c0 = kt * BK;
        __syncthreads();
        // ---- stage A: 8 scalar fp32 loads per octet, pack 4 bf16 -> ds_write_b64
#pragma unroll
        for (int r = 0; r < 4; ++r) {
            const int oct = aoct0 + r * 2;
            const float* src = inb + (size_t)(c0 + oct * 8) * HW + ap;
            float x[8];
#pragma unroll
            for (int j = 0; j < 8; ++j) x[j] = src[(size_t)j * HW];
            unsigned short h[8];
#pragma unroll
            for (int j = 0; j < 8; ++j) h[j] = f2bf(x[j]);
            *(ushort4*)&Ah[0][ap][oct * 8]     = make_ushort4(h[0], h[1], h[2], h[3]);
            *(ushort4*)&Ah[0][ap][oct * 8 + 4] = make_ushort4(h[4], h[5], h[6], h[7]);
            if constexpr (SPLIT) {
                unsigned short l[8];
#pragma unroll
                for (int j = 0; j < 8; ++j) l[j] = f2bf(x[j] - b2f(h[j]));
                *(ushort4*)&Ah[1][ap][oct * 8]     = make_ushort4(l[0], l[1], l[2], l[3]);
                *(ushort4*)&Ah[1][ap][oct * 8 + 4] = make_ushort4(l[4], l[5], l[6], l[7]);
            }
        }
        // ---- stage B: bf16 weights, contiguous rows
#pragma unroll
        for (int r = 0; r < BN * 8 / 256; ++r) {
            const int task = t + 256 * r;
            const int o = task >> 3, oct = task & 7;
            const unsigned short* src = Wh + (size_t)(o0 + o) * Cc + c0 + oct * 8;
            ushort4 w0 = *(const ushort4*)src;
            ushort4 w1 = *(const ushort4*)(src + 4);
            *(ushort4*)&Bh[0][o][oct * 8]     = w0;
            *(ushort4*)&Bh[0][o][oct * 8 + 4] = w1;
            if constexpr (SPLIT) {
                const unsigned short* srcl = Wl + (size_t)(o0 + o) * Cc + c0 + oct * 8;
                ushort4 l0 = *(const ushort4*)srcl;
                ushort4 l1 = *(const ushort4*)(srcl + 4);
                *(ushort4*)&Bh[1][o][oct * 8]     = l0;
                *(ushort4*)&Bh[1][o][oct * 8 + 4] = l1;
            }
        }
        __syncthreads();
        // ---- MFMA
#pragma unroll
        for (int ks = 0; ks < 2; ++ks) {
            const int col = ks * 32 + (lane >> 4) * 8;
            short8 af[4], al[4];
#pragma unroll
            for (int mt = 0; mt < 4; ++mt) {
                const int row = wm + mt * 16 + (lane & 15);
                af[mt] = ld8(&Ah[0][row][col]);
                if constexpr (SPLIT) al[mt] = ld8(&Ah[1][row][col]);
            }
            short8 bfr[NT], blr[NT];
#pragma unroll
            for (int nt = 0; nt < NT; ++nt) {
                const int row = wn + nt * 16 + (lane & 15);
                bfr[nt] = ld8(&Bh[0][row][col]);
                if constexpr (SPLIT) blr[nt] = ld8(&Bh[1][row][col]);
            }
#pragma unroll
            for (int mt = 0; mt < 4; ++mt)
#pragma unroll
                for (int nt = 0; nt < NT; ++nt) {
                    acc[mt][nt] = __builtin_amdgcn_mfma_f32_16x16x32_bf16(
                        af[mt], bfr[nt], acc[mt][nt], 0, 0, 0);
                    if constexpr (SPLIT) {
                        acc[mt][nt] = __builtin_amdgcn_mfma_f32_16x16x32_bf16(
                            al[mt], bfr[nt], acc[mt][nt], 0, 0, 0);
                        acc[mt][nt] = __builtin_amdgcn_mfma_f32_16x16x32_bf16(
                            af[mt], blr[nt], acc[mt][nt], 0, 0, 0);
                    }
                }
        }
    }
    // ---- epilogue: D row=(lane>>4)*4+reg (p), col=lane&15 (o); add bias
    const int oc = lane & 15, quad = lane >> 4;
#pragma unroll
    for (int nt = 0; nt < NT; ++nt) {
        const int o = o0 + wn + nt * 16 + oc;
        const float bs = bias[o];
#pragma unroll
        for (int mt = 0; mt < 4; ++mt) {
#pragma unroll
            for (int r = 0; r < 4; ++r) {
                const int p = p0 + wm + mt * 16 + quad * 4 + r;
                outT[((size_t)b * HW + p) * COUT + o] = acc[mt][nt][r] + bs;
            }
        }
    }
}

// ---------------------------------------------------------------------------
// Scores. mode0 (blockIdx.z==0): block=(b,w): eH[h][k]=dot_c(pq[:,h,w],pk[:,k,w])
//         mode1: block=(b,h): eW[w][k]=dot_c(pq[:,h,w],pk[:,h,k])
// S layout: [b][h][w][128], first 64 = eH, next 64 = eW. Mask applied in softmax.
// ---------------------------------------------------------------------------
__global__ __launch_bounds__(256) void scores_kernel(
    const float* __restrict__ pqT, const float* __restrict__ pkT,
    float* __restrict__ S)
{
    const int x    = blockIdx.x;   // w (mode0) or h (mode1)
    const int b    = blockIdx.y;
    const int mode = blockIdx.z;
    __shared__ float Q[64][65];
    __shared__ float K[64][65];
    for (int idx = threadIdx.x; idx < 4096; idx += 256) {
        int r = idx >> 6, c = idx & 63;
        int p = mode ? (x * Ww + r) : (r * Ww + x);
        size_t g = ((size_t)b * HW + p) * 64 + c;
        Q[r][c] = pqT[g];
        K[r][c] = pkT[g];
    }
    __syncthreads();
    const int qr = threadIdx.x >> 2;        // query row: h (mode0) / w (mode1)
    const int k0 = (threadIdx.x & 3) * 16;  // key range
    float acc[16];
#pragma unroll
    for (int j = 0; j < 16; ++j) acc[j] = 0.f;
#pragma unroll 4
    for (int c = 0; c < 64; ++c) {
        float qv = Q[qr][c];
#pragma unroll
        for (int j = 0; j < 16; ++j)
            acc[j] = fmaf(qv, K[k0 + j][c], acc[j]);
    }
    size_t o = mode ? (((size_t)(b * Hh + x) * Ww + qr) * 128 + 64 + k0)
                    : (((size_t)(b * Hh + qr) * Ww + x) * 128 + k0);
#pragma unroll
    for (int j = 0; j < 16; ++j) S[o + j] = acc[j];
}

// ---------------------------------------------------------------------------
// Softmax over 128 entries per (b,h,w); diag mask (eH[k==h] = -inf) here.
// ---------------------------------------------------------------------------
__global__ __launch_bounds__(256) void softmax_kernel(float* __restrict__ S)
{
    const int wave = threadIdx.x >> 6;
    const int lane = threadIdx.x & 63;
    const size_t row = (size_t)blockIdx.x * 4 + wave;   // (b*H + h)*W + w
    const int h = (int)((row / Ww) % Hh);
    float* p = S + row * 128;
    float s0 = p[lane], s1 = p[lane + 64];
    if (lane == h) s0 = -INFINITY;
    float m = fmaxf(s0, s1);
#pragma unroll
    for (int off = 32; off > 0; off >>= 1) m = fmaxf(m, __shfl_xor(m, off));
    float e0 = __expf(s0 - m), e1 = __expf(s1 - m);
    float s = e0 + e1;
#pragma unroll
    for (int off = 32; off > 0; off >>= 1) s += __shfl_xor(s, off);
    float inv = 1.0f / s;
    p[lane]      = e0 * inv;
    p[lane + 64] = e1 * inv;
}

// ---------------------------------------------------------------------------
// outH: block=(b,w): TH[b][h][w][c] = sum_k pvT[b][k*W+w][c] * aH[h][k]
// ---------------------------------------------------------------------------
__global__ __launch_bounds__(256) void outH_kernel(
    const float* __restrict__ S, const float* __restrict__ pvT,
    float* __restrict__ TH)
{
    const int w = blockIdx.x;
    const int b = blockIdx.y;
    __shared__ float A[64][65];   // [h][k]
    __shared__ float P[64][68];   // [k][c']
    for (int idx = threadIdx.x; idx < 4096; idx += 256) {
        int h = idx >> 6, k = idx & 63;
        A[h][k] = S[(((size_t)(b * Hh + h) * Ww) + w) * 128 + k];
    }
    const int cg = (threadIdx.x & 15) * 4;
    const int hg = (threadIdx.x >> 4) * 4;
    for (int ct = 0; ct < 8; ++ct) {
        __syncthreads();
        for (int idx = threadIdx.x; idx < 1024; idx += 256) {
            int k = idx >> 4, c4 = idx & 15;
            *(float4*)(&P[k][c4 * 4]) =
                *(const float4*)(pvT + ((size_t)b * HW + k * Ww + w) * 512 + ct * 64 + c4 * 4);
        }
        __syncthreads();
        float acc[4][4];
#pragma unroll
        for (int i = 0; i < 4; ++i)
#pragma unroll
            for (int j = 0; j < 4; ++j) acc[i][j] = 0.f;
        for (int k = 0; k < 64; ++k) {
            float4 p4 = *(const float4*)(&P[k][cg]);
            float pvv[4] = {p4.x, p4.y, p4.z, p4.w};
            float av[4];
#pragma unroll
            for (int j = 0; j < 4; ++j) av[j] = A[hg + j][k];
#pragma unroll
            for (int i = 0; i < 4; ++i)
#pragma unroll
                for (int j = 0; j < 4; ++j)
                    acc[i][j] = fmaf(pvv[i], av[j], acc[i][j]);
        }
#pragma unroll
        for (int j = 0; j < 4; ++j) {
            float4 o4 = make_float4(acc[0][j], acc[1][j], acc[2][j], acc[3][j]);
            *(float4*)(TH + (((size_t)(b * Hh + hg + j) * Ww) + w) * 512 + ct * 64 + cg) = o4;
        }
    }
}

// ---------------------------------------------------------------------------
// outW + finalize: block=(b,h):
// out[b][c][h][w] = gamma*(TH[b][h][w][c] + sum_k pvT[b][h*W+k][c]*aW[w][k]) + v
// ---------------------------------------------------------------------------
__global__ __launch_bounds__(256) void outW_final_kernel(
    const float* __restrict__ S, const float* __restrict__ pvT,
    const float* __restrict__ TH, const float* __restrict__ vin,
    const float* __restrict__ gamma_p, float* __restrict__ out)
{
    const int h = blockIdx.x;
    const int b = blockIdx.y;
    const float gamma = gamma_p[0];
    __shared__ float A[64][65];    // [w][k]
    __shared__ float P[64][68];    // [k][c']
    __shared__ float T2[64][68];   // [w][c']
    for (int idx = threadIdx.x; idx < 4096; idx += 256) {
        int w_ = idx >> 6, k = idx & 63;
        A[w_][k] = S[(((size_t)(b * Hh + h) * Ww) + w_) * 128 + 64 + k];
    }
    const int cg = (threadIdx.x >> 4) * 4;
    const int wg = (threadIdx.x & 15) * 4;
    for (int ct = 0; ct < 8; ++ct) {
        __syncthreads();
        for (int idx = threadIdx.x; idx < 1024; idx += 256) {
            int r = idx >> 4, c4 = idx & 15;
            *(float4*)(&P[r][c4 * 4]) =
                *(const float4*)(pvT + ((size_t)b * HW + h * Ww + r) * 512 + ct * 64 + c4 * 4);
            *(float4*)(&T2[r][c4 * 4]) =
                *(const float4*)(TH + (((size_t)(b * Hh + h) * Ww) + r) * 512 + ct * 64 + c4 * 4);
        }
        __syncthreads();
        float acc[4][4];
#pragma unroll
        for (int i = 0; i < 4; ++i)
#pragma unroll
            for (int j = 0; j < 4; ++j) acc[i][j] = 0.f;
        for (int k = 0; k < 64; ++k) {
            float4 p4 = *(const float4*)(&P[k][cg]);
            float pvv[4] = {p4.x, p4.y, p4.z, p4.w};
            float av[4];
#pragma unroll
            for (int j = 0; j < 4; ++j) av[j] = A[wg + j][k];
#pragma unroll
            for (int i = 0; i < 4; ++i)
#pragma unroll
                for (int j = 0; j < 4; ++j)
                    acc[i][j] = fmaf(pvv[i], av[j], acc[i][j]);
        }
#pragma unroll
        for (int i = 0; i < 4; ++i) {
            int c = ct * 64 + cg + i;
            size_t obase = ((size_t)(b * Cc + c) * HW) + (size_t)h * Ww + wg;
            float4 vv = *(const float4*)(vin + obase);
            float4 o4;
            o4.x = gamma * (acc[i][0] + T2[wg + 0][cg + i]) + vv.x;
            o4.y = gamma * (acc[i][1] + T2[wg + 1][cg + i]) + vv.y;
            o4.z = gamma * (acc[i][2] + T2[wg + 2][cg + i]) + vv.z;
            o4.w = gamma * (acc[i][3] + T2[wg + 3][cg + i]) + vv.w;
            *(float4*)(out + obase) = o4;
        }
    }
}

// ---------------------------------------------------------------------------
extern "C" void kernel_launch(void* const* d_in, const int* in_sizes, int n_in,
                              void* d_out, int out_size, void* d_ws, size_t ws_size,
                              hipStream_t stream)
{
    const float* q   = (const float*)d_in[0];
    const float* k   = (const float*)d_in[1];
    const float* v   = (const float*)d_in[2];
    const float* Wq  = (const float*)d_in[3];
    const float* bq  = (const float*)d_in[4];
    const float* Wk  = (const float*)d_in[5];
    const float* bk  = (const float*)d_in[6];
    const float* Wv  = (const float*)d_in[7];
    const float* bv  = (const float*)d_in[8];
    const float* gam = (const float*)d_in[9];
    float* out = (float*)d_out;
    float* ws  = (float*)d_ws;

    // ws layout (floats): pqT[8][4096][64], pkT same, pvT[8][4096][512],
    // S[8][64][64][128], TH[8][64][64][512]  -> 160 MiB total.
    float* pqT = ws;
    float* pkT = ws + 2097152;
    float* pvT = ws + 4194304;
    float* S   = ws + 20971520;
    float* TH  = ws + 25165824;

    // bf16 weights live at the START of the S region: written by wconv, read
    // by the proj kernels, then dead before scores_kernel overwrites S.
    unsigned short* wsc = (unsigned short*)S;
    const unsigned short* Wqh = wsc;
    const unsigned short* Wql = wsc + 32768;
    const unsigned short* Wkh = wsc + 65536;
    const unsigned short* Wkl = wsc + 98304;
    const unsigned short* Wvh = wsc + 131072;

    wconv_kernel<<<1280, 256, 0, stream>>>(Wq, Wk, Wv, wsc);
    proj_mfma_kernel<64, true ><<<dim3(32, 1, 8), 256, 0, stream>>>(q, Wqh, Wql, bq,  64, pqT);
    proj_mfma_kernel<64, true ><<<dim3(32, 1, 8), 256, 0, stream>>>(k, Wkh, Wkl, bk,  64, pkT);
    proj_mfma_kernel<128,false><<<dim3(32, 4, 8), 256, 0, stream>>>(v, Wvh, Wvh, bv, 512, pvT);
    scores_kernel<<<dim3(64, 8, 2), 256, 0, stream>>>(pqT, pkT, S);
    softmax_kernel<<<8192, 256, 0, stream>>>(S);
    outH_kernel<<<dim3(64, 8), 256, 0, stream>>>(S, pvT, TH);
    outW_final_kernel<<<dim3(64, 8), 256, 0, stream>>>(S, pvT, TH, v, gam, out);
}